// Round 2
// baseline (365.749 us; speedup 1.0000x reference)
//
#include <hip/hip_runtime.h>
#include <math.h>
#include <stddef.h>

#define BB 1024
#define LL 2048
#define EE 16
#define DD 48    // F*E
#define N1 200
#define N2 80
#define NSPLIT 4
#define PPB (LL / NSPLIT)    // 512 positions per block
#define ITERS (PPB / 256)    // 2 per thread

// ---------------- Kernel A: embed + attention pooling + X_series/mask write ----------------
// grid (B, NSPLIT), 256 threads; single-pass gather with ids prefetched and
// item vector held in SGPRs (block-uniform via readfirstlane).
__global__ __launch_bounds__(256, 4) void pool_kernel(
    const int* __restrict__ ig, const int* __restrict__ ish, const int* __restrict__ ic,
    const int* __restrict__ vg, const int* __restrict__ vs, const int* __restrict__ vc,
    const float* __restrict__ emb,
    float* __restrict__ Xs,    // [B,L,48] (part of d_out)
    float* __restrict__ Msk,   // [B,L]   (part of d_out)
    float* __restrict__ X,     // [B,96]  (ws) - item half written here
    float* __restrict__ P)     // [B,NSPLIT,48] (ws) - partial pooled
{
    const int b   = blockIdx.x;
    const int s   = blockIdx.y;
    const int tid = threadIdx.x;

    __shared__ float item[DD];
    if (tid < DD) {
        int f = tid >> 4, e = tid & 15;
        int id = (f == 0) ? ig[b] : (f == 1) ? ish[b] : ic[b];
        float v = emb[(size_t)id * EE + e];
        item[tid] = v;
        if (s == 0) X[(size_t)b * 96 + tid] = v;  // X_item part
    }
    __syncthreads();

    // block-uniform item vector -> SGPRs (no VGPR cost)
    float its[DD];
#pragma unroll
    for (int j = 0; j < DD; ++j)
        its[j] = __int_as_float(__builtin_amdgcn_readfirstlane(__float_as_int(item[j])));

    const float4* __restrict__ emb4 = (const float4*)emb;
    const int base = s * PPB;
    const int* vgb = vg + (size_t)b * LL + base;
    const int* vsb = vs + (size_t)b * LL + base;
    const int* vcb = vc + (size_t)b * LL + base;
    float4* __restrict__ Xs4 = (float4*)(Xs + (size_t)b * LL * DD) + (size_t)base * 12;
    float* mb = Msk + (size_t)b * LL + base;

    // prefetch all ids (independent loads, issue together)
    int pid[ITERS][3];
#pragma unroll
    for (int it = 0; it < ITERS; ++it) {
        const int l = tid + it * 256;
        pid[it][0] = vgb[l];
        pid[it][1] = vsb[l];
        pid[it][2] = vcb[l];
    }

    float pooled[DD];
#pragma unroll
    for (int j = 0; j < DD; ++j) pooled[j] = 0.f;

#pragma unroll
    for (int it = 0; it < ITERS; ++it) {
        const int l = tid + it * 256;
        float4 v[12];
#pragma unroll
        for (int f = 0; f < 3; ++f) {
            const float4* bp = emb4 + (size_t)pid[it][f] * 4;
#pragma unroll
            for (int q = 0; q < 4; ++q) v[f * 4 + q] = bp[q];
        }
        float score = 0.f;
#pragma unroll
        for (int r = 0; r < 12; ++r) {
            const int j = r * 4;
            score += v[r].x * its[j] + v[r].y * its[j + 1] +
                     v[r].z * its[j + 2] + v[r].w * its[j + 3];
        }
        const float valid = (pid[it][0] != 0) ? 1.f : 0.f;
        mb[l] = valid;
        const float sm = score * valid;
#pragma unroll
        for (int r = 0; r < 12; ++r) {
            Xs4[(size_t)l * 12 + r] = v[r];
            const int j = r * 4;
            pooled[j]     += sm * v[r].x;
            pooled[j + 1] += sm * v[r].y;
            pooled[j + 2] += sm * v[r].z;
            pooled[j + 3] += sm * v[r].w;
        }
    }

    // reduce pooled[48] across 256 threads
#pragma unroll
    for (int j = 0; j < DD; ++j) {
        float v = pooled[j];
        for (int off = 32; off; off >>= 1) v += __shfl_xor(v, off);
        pooled[j] = v;
    }
    __shared__ float wsum[4][DD];
    const int wave = tid >> 6, lane = tid & 63;
    if (lane == 0) {
#pragma unroll
        for (int j = 0; j < DD; ++j) wsum[wave][j] = pooled[j];
    }
    __syncthreads();
    if (tid < DD) {
        float sv = wsum[0][tid] + wsum[1][tid] + wsum[2][tid] + wsum[3][tid];
        P[((size_t)b * NSPLIT + s) * DD + tid] = sv;
    }
}

// ---------------- Kernel B: H1 = LN(X @ W1 + b1), combining pooled partials ----------------
__global__ __launch_bounds__(256) void mlp1_kernel(
    const float* __restrict__ X, const float* __restrict__ P,
    const float* __restrict__ W1,
    const float* __restrict__ b1, const float* __restrict__ g1, const float* __restrict__ be1,
    float* __restrict__ H1)
{
    const int b = blockIdx.x, tid = threadIdx.x;
    __shared__ float xr[96];
    if (tid < DD) {
        xr[tid] = X[(size_t)b * 96 + tid];
    } else if (tid < 96) {
        const int j = tid - DD;
        const float* pp = P + (size_t)b * NSPLIT * DD + j;
        float sv = 0.f;
#pragma unroll
        for (int s = 0; s < NSPLIT; ++s) sv += pp[s * DD];
        xr[tid] = sv;
    }
    __syncthreads();

    float y = 0.f;
    if (tid < N1) {
        y = b1[tid];
        for (int k = 0; k < 96; ++k) y += xr[k] * W1[k * N1 + tid];
    }

    __shared__ float red[256], red2[256];
    float yy = (tid < N1) ? y : 0.f;
    red[tid] = yy; red2[tid] = yy * yy;
    __syncthreads();
    for (int s = 128; s; s >>= 1) {
        if (tid < s) { red[tid] += red[tid + s]; red2[tid] += red2[tid + s]; }
        __syncthreads();
    }
    __shared__ float msh, ish;
    if (tid == 0) {
        float m = red[0] / (float)N1;
        float v = red2[0] / (float)N1 - m * m;
        msh = m; ish = rsqrtf(v + 1e-3f);
    }
    __syncthreads();
    if (tid < N1) H1[(size_t)b * N1 + tid] = g1[tid] * (y - msh) * ish + be1[tid];
}

// ---------------- Kernel C: per-column batch stats (mean, 1/sqrt(var+eps)) ----------------
__global__ __launch_bounds__(256) void colstats_kernel(
    const float* __restrict__ H, int n, int rows,
    float* __restrict__ mout, float* __restrict__ isout)
{
    const int f = blockIdx.x, tid = threadIdx.x;
    float s = 0.f, s2 = 0.f;
    for (int r = tid; r < rows; r += 256) {
        float v = H[(size_t)r * n + f];
        s += v; s2 += v * v;
    }
    __shared__ float red[256], red2[256];
    red[tid] = s; red2[tid] = s2;
    __syncthreads();
    for (int st = 128; st; st >>= 1) {
        if (tid < st) { red[tid] += red[tid + st]; red2[tid] += red2[tid + st]; }
        __syncthreads();
    }
    if (tid == 0) {
        float m = red[0] / (float)rows;
        float v = red2[0] / (float)rows - m * m;
        mout[f] = m;
        isout[f] = rsqrtf(v + 1e-3f);
    }
}

// ---------------- Kernel D: H2 = LN(dice1(H1) @ W2 + b2) ----------------
__global__ __launch_bounds__(256) void mlp2_kernel(
    const float* __restrict__ H1, const float* __restrict__ m1, const float* __restrict__ is1,
    const float* __restrict__ a1,
    const float* __restrict__ W2, const float* __restrict__ b2, const float* __restrict__ g2,
    const float* __restrict__ be2,
    float* __restrict__ H2)
{
    const int b = blockIdx.x, tid = threadIdx.x;
    __shared__ float d1[N1];
    if (tid < N1) {
        float h  = H1[(size_t)b * N1 + tid];
        float xn = (h - m1[tid]) * is1[tid];
        float p  = 1.f / (1.f + expf(-xn));
        d1[tid]  = h * (p + a1[tid] * (1.f - p));
    }
    __syncthreads();

    float y = 0.f;
    if (tid < N2) {
        y = b2[tid];
        for (int k = 0; k < N1; ++k) y += d1[k] * W2[k * N2 + tid];
    }

    __shared__ float red[256], red2[256];
    float yy = (tid < N2) ? y : 0.f;
    red[tid] = yy; red2[tid] = yy * yy;
    __syncthreads();
    for (int s = 128; s; s >>= 1) {
        if (tid < s) { red[tid] += red[tid + s]; red2[tid] += red2[tid + s]; }
        __syncthreads();
    }
    __shared__ float msh, ish;
    if (tid == 0) {
        float m = red[0] / (float)N2;
        float v = red2[0] / (float)N2 - m * m;
        msh = m; ish = rsqrtf(v + 1e-3f);
    }
    __syncthreads();
    if (tid < N2) H2[(size_t)b * N2 + tid] = g2[tid] * (y - msh) * ish + be2[tid];
}

// ---------------- Kernel F: out = softmax(dice2(H2) @ W3 + b3) ----------------
__global__ __launch_bounds__(256) void head_kernel(
    const float* __restrict__ H2, const float* __restrict__ m2, const float* __restrict__ is2,
    const float* __restrict__ a2,
    const float* __restrict__ W3, const float* __restrict__ b3,
    float* __restrict__ out)
{
    const int b = blockIdx.x * 256 + threadIdx.x;
    if (b >= BB) return;
    float z0 = b3[0], z1 = b3[1];
    for (int k = 0; k < N2; ++k) {
        float h  = H2[(size_t)b * N2 + k];
        float xn = (h - m2[k]) * is2[k];
        float p  = 1.f / (1.f + expf(-xn));
        float d  = h * (p + a2[k] * (1.f - p));
        z0 += d * W3[k * 2 + 0];
        z1 += d * W3[k * 2 + 1];
    }
    float mx = fmaxf(z0, z1);
    float e0 = expf(z0 - mx), e1 = expf(z1 - mx);
    float inv = 1.f / (e0 + e1);
    out[(size_t)b * 2 + 0] = e0 * inv;
    out[(size_t)b * 2 + 1] = e1 * inv;
}

extern "C" void kernel_launch(void* const* d_in, const int* in_sizes, int n_in,
                              void* d_out, int out_size, void* d_ws, size_t ws_size,
                              hipStream_t stream) {
    const int*   ig  = (const int*)  d_in[0];
    const int*   ish = (const int*)  d_in[1];
    const int*   ic  = (const int*)  d_in[2];
    const int*   vg  = (const int*)  d_in[3];
    const int*   vs  = (const int*)  d_in[4];
    const int*   vc  = (const int*)  d_in[5];
    const float* emb = (const float*)d_in[6];
    const float* W1  = (const float*)d_in[7];
    const float* b1  = (const float*)d_in[8];
    const float* g1  = (const float*)d_in[9];
    const float* be1 = (const float*)d_in[10];
    const float* a1  = (const float*)d_in[11];
    const float* W2  = (const float*)d_in[12];
    const float* b2  = (const float*)d_in[13];
    const float* g2  = (const float*)d_in[14];
    const float* be2 = (const float*)d_in[15];
    const float* a2  = (const float*)d_in[16];
    const float* W3  = (const float*)d_in[17];
    const float* b3  = (const float*)d_in[18];

    float* out  = (float*)d_out;                       // [B,2]
    float* Xs   = out + (size_t)BB * 2;                // [B,L,48]
    float* Msk  = Xs + (size_t)BB * LL * DD;           // [B,L]

    float* X    = (float*)d_ws;                        // [B,96]
    float* P    = X + (size_t)BB * 96;                 // [B,NSPLIT,48]
    float* H1   = P + (size_t)BB * NSPLIT * DD;        // [B,200]
    float* H2v  = H1 + (size_t)BB * N1;                // [B,80]
    float* m1   = H2v + (size_t)BB * N2;               // [200]
    float* is1  = m1 + N1;                             // [200]
    float* m2   = is1 + N1;                            // [80]
    float* is2  = m2 + N2;                             // [80]

    pool_kernel<<<dim3(BB, NSPLIT), 256, 0, stream>>>(ig, ish, ic, vg, vs, vc, emb,
                                                      Xs, Msk, X, P);
    mlp1_kernel<<<BB, 256, 0, stream>>>(X, P, W1, b1, g1, be1, H1);
    colstats_kernel<<<N1, 256, 0, stream>>>(H1, N1, BB, m1, is1);
    mlp2_kernel<<<BB, 256, 0, stream>>>(H1, m1, is1, a1, W2, b2, g2, be2, H2v);
    colstats_kernel<<<N2, 256, 0, stream>>>(H2v, N2, BB, m2, is2);
    head_kernel<<<(BB + 255) / 256, 256, 0, stream>>>(H2v, m2, is2, a2, W3, b3, out);
}

// Round 3
// 210.322 us; speedup vs baseline: 1.7390x; 1.7390x over previous
//
#include <hip/hip_runtime.h>
#include <math.h>
#include <stddef.h>

#define BB 1024
#define LL 2048
#define EE 16
#define DD 48    // F*E
#define N1 200
#define N2 80
#define NSPLIT 8
#define PPB (LL / NSPLIT)      // 256 positions per block
#define POS_PER_IT 64          // 256 threads / 4 lanes-per-position
#define ITERS (PPB / POS_PER_IT) // 4

// ---------------- Kernel A: embed + attention pooling + X_series/mask write ----------------
// grid (B, NSPLIT), 256 threads. 4 lanes cooperate on one position: lane q owns
// float4 #q of each of the 3 feature embedding rows (12 floats of the 48).
__global__ __launch_bounds__(256, 6) void pool_kernel(
    const int* __restrict__ ig, const int* __restrict__ ish, const int* __restrict__ ic,
    const int* __restrict__ vg, const int* __restrict__ vs, const int* __restrict__ vc,
    const float* __restrict__ emb,
    float* __restrict__ Xs,    // [B,L,48] (part of d_out)
    float* __restrict__ Msk,   // [B,L]   (part of d_out)
    float* __restrict__ X,     // [B,96]  (ws) - item half
    float* __restrict__ P)     // [B,NSPLIT,48] (ws) - partial pooled
{
    const int b   = blockIdx.x;
    const int s   = blockIdx.y;
    const int tid = threadIdx.x;
    const int q   = tid & 3;        // quad lane: which float4 of each row
    const int pl  = tid >> 2;       // local position 0..63

    __shared__ float item[DD];
    if (tid < DD) {
        int f = tid >> 4, e = tid & 15;
        int id = (f == 0) ? ig[b] : (f == 1) ? ish[b] : ic[b];
        float v = emb[(size_t)id * EE + e];
        item[tid] = v;
        if (s == 0) X[(size_t)b * 96 + tid] = v;  // X_item part
    }
    __syncthreads();

    // this lane's slice of the item vector: float4 #q of each feature
    float4 it4[3];
#pragma unroll
    for (int f = 0; f < 3; ++f) it4[f] = ((const float4*)item)[f * 4 + q];

    const float4* __restrict__ emb4 = (const float4*)emb;
    const int base = s * PPB;
    const int* vgb = vg + (size_t)b * LL + base;
    const int* vsb = vs + (size_t)b * LL + base;
    const int* vcb = vc + (size_t)b * LL + base;
    float4* __restrict__ Xs4 = (float4*)(Xs + (size_t)b * LL * DD) + (size_t)base * 12;
    float* mb = Msk + (size_t)b * LL + base;

    // prefetch all ids (independent loads; quad-redundant but same cache line)
    int pg[ITERS], ps[ITERS], pc[ITERS];
#pragma unroll
    for (int it = 0; it < ITERS; ++it) {
        const int l = it * POS_PER_IT + pl;
        pg[it] = vgb[l]; ps[it] = vsb[l]; pc[it] = vcb[l];
    }

    float pooled[12];
#pragma unroll
    for (int j = 0; j < 12; ++j) pooled[j] = 0.f;

#pragma unroll
    for (int it = 0; it < ITERS; ++it) {
        const int l = it * POS_PER_IT + pl;
        float4 v0 = emb4[(size_t)pg[it] * 4 + q];
        float4 v1 = emb4[(size_t)ps[it] * 4 + q];
        float4 v2 = emb4[(size_t)pc[it] * 4 + q];

        float sc = v0.x * it4[0].x + v0.y * it4[0].y + v0.z * it4[0].z + v0.w * it4[0].w
                 + v1.x * it4[1].x + v1.y * it4[1].y + v1.z * it4[1].z + v1.w * it4[1].w
                 + v2.x * it4[2].x + v2.y * it4[2].y + v2.z * it4[2].z + v2.w * it4[2].w;
        sc += __shfl_xor(sc, 1);
        sc += __shfl_xor(sc, 2);   // full score in all 4 quad lanes

        const float valid = (pg[it] != 0) ? 1.f : 0.f;
        if (q == 0) mb[l] = valid;
        const float sm = sc * valid;

        const size_t o = (size_t)l * 12 + q;
        Xs4[o]     = v0;
        Xs4[o + 4] = v1;
        Xs4[o + 8] = v2;

        pooled[0] += sm * v0.x; pooled[1]  += sm * v0.y; pooled[2]  += sm * v0.z; pooled[3]  += sm * v0.w;
        pooled[4] += sm * v1.x; pooled[5]  += sm * v1.y; pooled[6]  += sm * v1.z; pooled[7]  += sm * v1.w;
        pooled[8] += sm * v2.x; pooled[9]  += sm * v2.y; pooled[10] += sm * v2.z; pooled[11] += sm * v2.w;
    }

    // reduce over positions within the wave (keep q-slices separate)
#pragma unroll
    for (int j = 0; j < 12; ++j) {
        float v = pooled[j];
        v += __shfl_xor(v, 4);
        v += __shfl_xor(v, 8);
        v += __shfl_xor(v, 16);
        v += __shfl_xor(v, 32);
        pooled[j] = v;
    }

    __shared__ float wsum[4][DD];
    const int wave = tid >> 6;
    if (pl == 0 || (tid & 63) < 4) { /* lanes 0..3 of each wave hold sums */ }
    if ((tid & 63) < 4) {
#pragma unroll
        for (int f = 0; f < 3; ++f)
#pragma unroll
            for (int e = 0; e < 4; ++e)
                wsum[wave][f * 16 + q * 4 + e] = pooled[f * 4 + e];
    }
    __syncthreads();
    if (tid < DD) {
        float sv = wsum[0][tid] + wsum[1][tid] + wsum[2][tid] + wsum[3][tid];
        P[((size_t)b * NSPLIT + s) * DD + tid] = sv;
    }
}

// ---------------- Kernel B: H1 = LN(X @ W1 + b1), combining pooled partials ----------------
__global__ __launch_bounds__(256) void mlp1_kernel(
    const float* __restrict__ X, const float* __restrict__ P,
    const float* __restrict__ W1,
    const float* __restrict__ b1, const float* __restrict__ g1, const float* __restrict__ be1,
    float* __restrict__ H1)
{
    const int b = blockIdx.x, tid = threadIdx.x;
    __shared__ float xr[96];
    if (tid < DD) {
        xr[tid] = X[(size_t)b * 96 + tid];
    } else if (tid < 96) {
        const int j = tid - DD;
        const float* pp = P + (size_t)b * NSPLIT * DD + j;
        float sv = 0.f;
#pragma unroll
        for (int s = 0; s < NSPLIT; ++s) sv += pp[s * DD];
        xr[tid] = sv;
    }
    __syncthreads();

    float y = 0.f;
    if (tid < N1) {
        y = b1[tid];
        for (int k = 0; k < 96; ++k) y += xr[k] * W1[k * N1 + tid];
    }

    __shared__ float red[256], red2[256];
    float yy = (tid < N1) ? y : 0.f;
    red[tid] = yy; red2[tid] = yy * yy;
    __syncthreads();
    for (int s = 128; s; s >>= 1) {
        if (tid < s) { red[tid] += red[tid + s]; red2[tid] += red2[tid + s]; }
        __syncthreads();
    }
    __shared__ float msh, ish;
    if (tid == 0) {
        float m = red[0] / (float)N1;
        float v = red2[0] / (float)N1 - m * m;
        msh = m; ish = rsqrtf(v + 1e-3f);
    }
    __syncthreads();
    if (tid < N1) H1[(size_t)b * N1 + tid] = g1[tid] * (y - msh) * ish + be1[tid];
}

// ---------------- Kernel C: per-column batch stats (mean, 1/sqrt(var+eps)) ----------------
__global__ __launch_bounds__(256) void colstats_kernel(
    const float* __restrict__ H, int n, int rows,
    float* __restrict__ mout, float* __restrict__ isout)
{
    const int f = blockIdx.x, tid = threadIdx.x;
    float s = 0.f, s2 = 0.f;
    for (int r = tid; r < rows; r += 256) {
        float v = H[(size_t)r * n + f];
        s += v; s2 += v * v;
    }
    __shared__ float red[256], red2[256];
    red[tid] = s; red2[tid] = s2;
    __syncthreads();
    for (int st = 128; st; st >>= 1) {
        if (tid < st) { red[tid] += red[tid + st]; red2[tid] += red2[tid + st]; }
        __syncthreads();
    }
    if (tid == 0) {
        float m = red[0] / (float)rows;
        float v = red2[0] / (float)rows - m * m;
        mout[f] = m;
        isout[f] = rsqrtf(v + 1e-3f);
    }
}

// ---------------- Kernel D: H2 = LN(dice1(H1) @ W2 + b2) ----------------
__global__ __launch_bounds__(256) void mlp2_kernel(
    const float* __restrict__ H1, const float* __restrict__ m1, const float* __restrict__ is1,
    const float* __restrict__ a1,
    const float* __restrict__ W2, const float* __restrict__ b2, const float* __restrict__ g2,
    const float* __restrict__ be2,
    float* __restrict__ H2)
{
    const int b = blockIdx.x, tid = threadIdx.x;
    __shared__ float d1[N1];
    if (tid < N1) {
        float h  = H1[(size_t)b * N1 + tid];
        float xn = (h - m1[tid]) * is1[tid];
        float p  = 1.f / (1.f + expf(-xn));
        d1[tid]  = h * (p + a1[tid] * (1.f - p));
    }
    __syncthreads();

    float y = 0.f;
    if (tid < N2) {
        y = b2[tid];
        for (int k = 0; k < N1; ++k) y += d1[k] * W2[k * N2 + tid];
    }

    __shared__ float red[256], red2[256];
    float yy = (tid < N2) ? y : 0.f;
    red[tid] = yy; red2[tid] = yy * yy;
    __syncthreads();
    for (int s = 128; s; s >>= 1) {
        if (tid < s) { red[tid] += red[tid + s]; red2[tid] += red2[tid + s]; }
        __syncthreads();
    }
    __shared__ float msh, ish;
    if (tid == 0) {
        float m = red[0] / (float)N2;
        float v = red2[0] / (float)N2 - m * m;
        msh = m; ish = rsqrtf(v + 1e-3f);
    }
    __syncthreads();
    if (tid < N2) H2[(size_t)b * N2 + tid] = g2[tid] * (y - msh) * ish + be2[tid];
}

// ---------------- Kernel F: out = softmax(dice2(H2) @ W3 + b3) ----------------
__global__ __launch_bounds__(256) void head_kernel(
    const float* __restrict__ H2, const float* __restrict__ m2, const float* __restrict__ is2,
    const float* __restrict__ a2,
    const float* __restrict__ W3, const float* __restrict__ b3,
    float* __restrict__ out)
{
    const int b = blockIdx.x * 256 + threadIdx.x;
    if (b >= BB) return;
    float z0 = b3[0], z1 = b3[1];
    for (int k = 0; k < N2; ++k) {
        float h  = H2[(size_t)b * N2 + k];
        float xn = (h - m2[k]) * is2[k];
        float p  = 1.f / (1.f + expf(-xn));
        float d  = h * (p + a2[k] * (1.f - p));
        z0 += d * W3[k * 2 + 0];
        z1 += d * W3[k * 2 + 1];
    }
    float mx = fmaxf(z0, z1);
    float e0 = expf(z0 - mx), e1 = expf(z1 - mx);
    float inv = 1.f / (e0 + e1);
    out[(size_t)b * 2 + 0] = e0 * inv;
    out[(size_t)b * 2 + 1] = e1 * inv;
}

extern "C" void kernel_launch(void* const* d_in, const int* in_sizes, int n_in,
                              void* d_out, int out_size, void* d_ws, size_t ws_size,
                              hipStream_t stream) {
    const int*   ig  = (const int*)  d_in[0];
    const int*   ish = (const int*)  d_in[1];
    const int*   ic  = (const int*)  d_in[2];
    const int*   vg  = (const int*)  d_in[3];
    const int*   vs  = (const int*)  d_in[4];
    const int*   vc  = (const int*)  d_in[5];
    const float* emb = (const float*)d_in[6];
    const float* W1  = (const float*)d_in[7];
    const float* b1  = (const float*)d_in[8];
    const float* g1  = (const float*)d_in[9];
    const float* be1 = (const float*)d_in[10];
    const float* a1  = (const float*)d_in[11];
    const float* W2  = (const float*)d_in[12];
    const float* b2  = (const float*)d_in[13];
    const float* g2  = (const float*)d_in[14];
    const float* be2 = (const float*)d_in[15];
    const float* a2  = (const float*)d_in[16];
    const float* W3  = (const float*)d_in[17];
    const float* b3  = (const float*)d_in[18];

    float* out  = (float*)d_out;                       // [B,2]
    float* Xs   = out + (size_t)BB * 2;                // [B,L,48]
    float* Msk  = Xs + (size_t)BB * LL * DD;           // [B,L]

    float* X    = (float*)d_ws;                        // [B,96]
    float* P    = X + (size_t)BB * 96;                 // [B,NSPLIT,48]
    float* H1   = P + (size_t)BB * NSPLIT * DD;        // [B,200]
    float* H2v  = H1 + (size_t)BB * N1;                // [B,80]
    float* m1   = H2v + (size_t)BB * N2;               // [200]
    float* is1  = m1 + N1;                             // [200]
    float* m2   = is1 + N1;                            // [80]
    float* is2  = m2 + N2;                             // [80]

    pool_kernel<<<dim3(BB, NSPLIT), 256, 0, stream>>>(ig, ish, ic, vg, vs, vc, emb,
                                                      Xs, Msk, X, P);
    mlp1_kernel<<<BB, 256, 0, stream>>>(X, P, W1, b1, g1, be1, H1);
    colstats_kernel<<<N1, 256, 0, stream>>>(H1, N1, BB, m1, is1);
    mlp2_kernel<<<BB, 256, 0, stream>>>(H1, m1, is1, a1, W2, b2, g2, be2, H2v);
    colstats_kernel<<<N2, 256, 0, stream>>>(H2v, N2, BB, m2, is2);
    head_kernel<<<(BB + 255) / 256, 256, 0, stream>>>(H2v, m2, is2, a2, W3, b3, out);
}